// Round 6
// baseline (298.457 us; speedup 1.0000x reference)
//
#include <hip/hip_runtime.h>
#include <hip/hip_bf16.h>
#include <hip/hip_cooperative_groups.h>
#include <math.h>

namespace cg = cooperative_groups;

#define N 8192
#define TPB 256
#define BLKS 512               // 8 i-chunks x 64 j-slices, one task per block
#define JS 64                  // j-slices
#define SL (N / JS)            // 128 j's per slice
#define IT 4                   // i's per thread
#define IBT (TPB * IT)         // 1024 i's per chunk

// Reference f32 pipeline (verified absmax 0.0 in R2..R5):
//   i = round((log(512)-log(w))/log(1.2)); di = 128/1.2^i; qx = round(x/di-0.5)
// Bounds: i,j in [0,23] (5 bits), qx,qy in [0,1035] (11 bits).
// pack = (j<<27)|(i<<22)|(qy<<11)|qx is equality- AND order-isomorphic to the
// reference decimal int64 code (decimal fields never carry: 1035<1e4, 23<1e4).
__device__ __forceinline__ unsigned pack_code(float x, float y, float w, float h) {
    const float LOG_ALPHA = (float)log((double)1.2f);
    const float LOGW0     = (float)log(512.0);
    float i_f = rintf((LOGW0 - (float)log((double)w)) / LOG_ALPHA);
    float j_f = rintf((LOGW0 - (float)log((double)h)) / LOG_ALPHA);
    float pi  = (float)pow((double)1.2f, (double)i_f);
    float pj  = (float)pow((double)1.2f, (double)j_f);
    float qx  = rintf(x / (128.0f / pi) - 0.5f);
    float qy  = rintf(y / (128.0f / pj) - 0.5f);
    return ((unsigned)(int)j_f << 27) | ((unsigned)(int)i_f << 22)
         | ((unsigned)(int)qy << 11) | (unsigned)(int)qx;
}

// Single cooperative kernel, 5 phases separated by grid.sync():
//  A : codes + packed (code<<32|conf_bits) keys; zero out
//  B : per (i-chunk, j-slice): lose_i / notfirst_i partials (plain stores)
//  B2: OR-reduce flag partials -> flags[i]  (bit0=lose, bit1=notfirst)
//  C : per (i-chunk, j-slice): rank partial = #{first_j && code_j < code_i}
//  D : sum rank partials; winners scatter their index at their unique rank
__global__ void __launch_bounds__(TPB)
k_all(const float4* __restrict__ rects, const float* __restrict__ conf,
      unsigned* __restrict__ code32, unsigned long long* __restrict__ pairw,
      int* __restrict__ flags, int* __restrict__ flag_part,
      int* __restrict__ rank_part, int* __restrict__ out) {
    cg::grid_group grid = cg::this_grid();
    __shared__ unsigned long long s_w[SL];      // reused as u32 in phase C
    const int b = blockIdx.x, t = threadIdx.x;
    const int gid = b * TPB + t;
    const int ib = b >> 6;                      // i-chunk   0..7
    const int js = b & 63;                      // j-slice   0..63
    const int i0 = ib * IBT + t;

    // ---- A: codes (blocks 0..31 active) ----
    if (gid < N) {
        float4 r = rects[gid];
        unsigned c = pack_code(r.x, r.y, r.z, r.w);
        code32[gid] = c;
        pairw[gid]  = ((unsigned long long)c << 32)
                    | (unsigned long long)__float_as_uint(conf[gid]);
        out[gid] = 0;                           // padded unique slots must be 0
    }
    grid.sync();

    // ---- B: lose/notfirst partials ----
    {
        if (t < SL) s_w[t] = pairw[js * SL + t];
        unsigned long long wi[IT];
        #pragma unroll
        for (int m = 0; m < IT; ++m) wi[m] = pairw[i0 + m * TPB];
        __syncthreads();
        int l[IT] = {0,0,0,0}, f[IT] = {0,0,0,0};
        #pragma unroll 8
        for (int k = 0; k < SL; ++k) {
            unsigned long long wj = s_w[k];     // wave-uniform LDS broadcast
            int jg = js * SL + k;
            #pragma unroll
            for (int m = 0; m < IT; ++m) {
                bool ceq = (unsigned)(wj >> 32) == (unsigned)(wi[m] >> 32);
                bool g   = wj > wi[m];          // same code -> conf_j > conf_i
                bool e   = wj == wi[m];         // same code AND same conf
                bool d   = jg < i0 + m * TPB;   // j < i
                l[m] |= (int)(ceq & (g | (e & d)));
                f[m] |= (int)(ceq & d);         // earlier same-code j exists
            }
        }
        #pragma unroll
        for (int m = 0; m < IT; ++m)            // coalesced, no atomics
            flag_part[js * N + i0 + m * TPB] = l[m] | (f[m] << 1);
        __syncthreads();                        // s_w reused in phase C
    }
    grid.sync();

    // ---- B2: reduce flag partials ----
    if (gid < N) {
        int fl = 0;
        #pragma unroll
        for (int s = 0; s < JS; ++s) fl |= flag_part[s * N + gid];
        flags[gid] = fl;
    }
    grid.sync();

    // ---- C: rank partials (count first-occurrence codes below mine) ----
    {
        unsigned* s_v = (unsigned*)s_w;
        if (t < SL) {
            int j = js * SL + t;
            // non-first j masked to 0xFFFFFFFF (> any real code < 0xBD000000)
            s_v[t] = (flags[j] & 2) ? 0xFFFFFFFFu : code32[j];
        }
        unsigned ci[IT];
        #pragma unroll
        for (int m = 0; m < IT; ++m) ci[m] = code32[i0 + m * TPB];
        __syncthreads();
        int r[IT] = {0,0,0,0};
        #pragma unroll 8
        for (int k = 0; k < SL; ++k) {
            unsigned v = s_v[k];                // wave-uniform LDS broadcast
            #pragma unroll
            for (int m = 0; m < IT; ++m) r[m] += (int)(v < ci[m]);
        }
        #pragma unroll
        for (int m = 0; m < IT; ++m)            // coalesced, no atomics
            rank_part[js * N + i0 + m * TPB] = r[m];
    }
    grid.sync();

    // ---- D: sum partials, winners scatter ----
    if (gid < N) {
        int r = 0;
        #pragma unroll
        for (int s = 0; s < JS; ++s) r += rank_part[s * N + gid];
        if (!(flags[gid] & 1)) {
            // conf==0 edge: all-zero score column -> reference argmax -> 0
            out[r] = (conf[gid] == 0.0f) ? 0 : gid;
        }
    }
}

extern "C" void kernel_launch(void* const* d_in, const int* in_sizes, int n_in,
                              void* d_out, int out_size, void* d_ws, size_t ws_size,
                              hipStream_t stream) {
    const float4* rects = (const float4*)d_in[0];   // (8192, 4) f32
    const float*  conf  = (const float*)d_in[1];    // (8192,)  f32
    int* out = (int*)d_out;                         // int32 indices

    char* ws = (char*)d_ws;
    unsigned long long* pairw = (unsigned long long*)ws;      // 64 KiB (8B-aligned first)
    unsigned* code32    = (unsigned*)(ws + N * 8);            // 32 KiB
    int*      flags     = (int*)(ws + N * 12);                // 32 KiB
    int*      flag_part = (int*)(ws + N * 16);                // JS*N*4 = 2 MiB
    int*      rank_part = (int*)(ws + N * 16 + JS * N * 4);   // 2 MiB

    void* args[] = { (void*)&rects, (void*)&conf, (void*)&code32, (void*)&pairw,
                     (void*)&flags, (void*)&flag_part, (void*)&rank_part, (void*)&out };
    hipLaunchCooperativeKernel((const void*)k_all, dim3(BLKS), dim3(TPB),
                               args, 0, stream);
}

// Round 7
// 88.011 us; speedup vs baseline: 3.3911x; 3.3911x over previous
//
#include <hip/hip_runtime.h>
#include <math.h>

#define N 8192
// K1: 32 i-chunks (256 i each) x 16 j-slices (512 j each) = 512 blocks
#define K1_TPB 256
#define K1_IB  32
#define K1_JS  16
#define K1_SL  (N / K1_JS)     // 512
// K2: 256 blocks, 32 i's per block, 8 j-segments x 1024 j
#define K2_TPB 256

// Reference f32 pipeline (verified absmax 0.0 in R2..R6):
//   i = round((log(512)-log(w))/log(1.2)); di = 128/1.2^i; qx = round(x/di-0.5)
// Bounds: i,j in [0,23] (5 bits), qx,qy in [0,1035] (11 bits).
// pack = (j<<27)|(i<<22)|(qy<<11)|qx is equality- AND order-isomorphic to the
// reference decimal int64 code (decimal fields never carry: 1035<1e4, 23<1e4).
// 1.2^i comes from an LDS table holding (float)pow((double)1.2f,(double)k) --
// bit-identical to the verified per-thread pow calls (same fn, same args).
__device__ __forceinline__ unsigned pack_code_tab(float x, float y, float w, float h,
                                                  const float* __restrict__ s_pow) {
    const float LOG_ALPHA = (float)log((double)1.2f);
    const float LOGW0     = (float)log(512.0);
    float i_f = rintf((LOGW0 - (float)log((double)w)) / LOG_ALPHA);
    float j_f = rintf((LOGW0 - (float)log((double)h)) / LOG_ALPHA);
    int ii = (int)i_f, jj = (int)j_f;
    float qx = rintf(x / (128.0f / s_pow[ii]) - 0.5f);
    float qy = rintf(y / (128.0f / s_pow[jj]) - 0.5f);
    return ((unsigned)jj << 27) | ((unsigned)ii << 22)
         | ((unsigned)(int)qy << 11) | (unsigned)(int)qx;
}

// K1: lose partials. Block (ib, js): stages 512 j-keys in LDS (recomputed from
// rects -- no separate codes kernel), each thread tests its 1 i against them.
// Compare = 4 v_cmp + scalar-pipe mask logic; bool accumulator stays in SGPRs.
__global__ void __launch_bounds__(K1_TPB)
k_flags(const float4* __restrict__ rects, const float* __restrict__ conf,
        unsigned* __restrict__ code32, unsigned char* __restrict__ flag16,
        int* __restrict__ out) {
    __shared__ unsigned long long s_w[K1_SL];
    __shared__ float s_pow[24];
    const int t  = threadIdx.x;
    const int ib = blockIdx.x, js = blockIdx.y;
    const int jb = js * K1_SL;
    const int i  = ib * K1_TPB + t;

    if (t < 24) s_pow[t] = (float)pow((double)1.2f, (double)t);
    __syncthreads();

    // own i key (recomputed; dedup handled by js==0 persisting code32)
    float4 ri = rects[i];
    unsigned ci = pack_code_tab(ri.x, ri.y, ri.z, ri.w, s_pow);
    unsigned long long wi = ((unsigned long long)ci << 32)
                          | (unsigned long long)__float_as_uint(conf[i]);
    if (js == 0) { code32[i] = ci; out[i] = 0; }   // out zero: padded slots = 0

    // stage this block's 512 j-keys (2 per thread, coalesced float4 loads)
    #pragma unroll
    for (int c = 0; c < 2; ++c) {
        int j = jb + t + c * K1_TPB;
        float4 rj = rects[j];
        unsigned cj = pack_code_tab(rj.x, rj.y, rj.z, rj.w, s_pow);
        s_w[t + c * K1_TPB] = ((unsigned long long)cj << 32)
                            | (unsigned long long)__float_as_uint(conf[j]);
    }
    __syncthreads();

    // j beats i iff same code && (conf_j > conf_i || (conf_j==conf_i && j<i))
    bool lose = false;
    #pragma unroll 8
    for (int k = 0; k < K1_SL; ++k) {
        unsigned long long wj = s_w[k];            // wave-uniform LDS broadcast
        bool ceq = (unsigned)(wj >> 32) == ci;     // v_cmp_eq_u32
        bool g   = wj > wi;                        // v_cmp_gt_u64 (conf order)
        bool e   = wj == wi;                       // v_cmp_eq_u64
        bool d   = (jb + k) < i;                   // v_cmp (uniform vs lane)
        lose = lose | (ceq & (g | (e & d)));       // s_and/s_or on masks
    }
    flag16[i * K1_JS + js] = lose ? 1 : 0;         // byte partial, RMW-safe
}

// K2: rank + scatter fused. Each block OR-reduces the 16 lose-bytes of ALL
// 8192 j (coalesced uint4), stages winner-masked codes in LDS (32 KB), then
// (32 i x 8 segs) count winners-with-smaller-code via ds_read_b128.
// rank_i = #winners with code < code_i = #distinct codes below mine
// (exactly one winner per distinct code). Winners scatter out[rank] = i.
__global__ void __launch_bounds__(K2_TPB)
k_rank(const unsigned* __restrict__ code32, const uint4* __restrict__ flag16v,
       const float* __restrict__ conf, int* __restrict__ out) {
    __shared__ unsigned s_v[N];                    // 32 KiB
    __shared__ int s_r[K2_TPB];
    const int t = threadIdx.x, b = blockIdx.x;

    #pragma unroll 4
    for (int c = 0; c < N / K2_TPB; ++c) {         // 32 j's per thread
        int j = t + c * K2_TPB;
        uint4 f = flag16v[j];                      // 16 lose bytes, coalesced
        unsigned lose = f.x | f.y | f.z | f.w;
        unsigned code = code32[j];
        // losers -> 0xFFFFFFFF (> any real code < 0xC0000000): never counted
        s_v[j] = lose ? 0xFFFFFFFFu : code;
    }
    __syncthreads();

    const int il = t & 31, seg = t >> 5;
    const int i = b * 32 + il;
    unsigned ci = s_v[i];                          // masked; ok (losers skip)
    const uint4* sv4 = (const uint4*)&s_v[seg * 1024];  // 16B-aligned
    int r = 0;
    #pragma unroll 8
    for (int k = 0; k < 256; ++k) {                // 1024 j's per seg, x4 vec
        uint4 v = sv4[k];                          // 2-way multicast: free
        r += (int)(v.x < ci) + (int)(v.y < ci) + (int)(v.z < ci) + (int)(v.w < ci);
    }
    s_r[seg * 32 + il] = r;
    __syncthreads();

    if (t < 32) {
        int gi = b * 32 + t;
        int rr = 0;
        #pragma unroll
        for (int s = 0; s < 8; ++s) rr += s_r[s * 32 + t];   // bank-clean
        if (s_v[gi] != 0xFFFFFFFFu) {              // winner
            // conf==0 edge: all-zero score column -> reference argmax -> 0
            out[rr] = (conf[gi] == 0.0f) ? 0 : gi;
        }
    }
}

extern "C" void kernel_launch(void* const* d_in, const int* in_sizes, int n_in,
                              void* d_out, int out_size, void* d_ws, size_t ws_size,
                              hipStream_t stream) {
    const float4* rects = (const float4*)d_in[0];   // (8192, 4) f32
    const float*  conf  = (const float*)d_in[1];    // (8192,)  f32
    int* out = (int*)d_out;                         // int32 indices

    char* ws = (char*)d_ws;
    unsigned*      code32 = (unsigned*)ws;                    // 32 KiB
    unsigned char* flag16 = (unsigned char*)(ws + N * 4);     // 128 KiB, 16B/row

    k_flags<<<dim3(K1_IB, K1_JS), K1_TPB, 0, stream>>>(rects, conf, code32, flag16, out);
    k_rank <<<dim3(N / 32),       K2_TPB, 0, stream>>>(code32, (const uint4*)flag16, conf, out);
}